// Round 2
// baseline (541.053 us; speedup 1.0000x reference)
//
#include <hip/hip_runtime.h>

// Segment mean via fixed-capacity bucket sort + atomic-free gather reduction.
// N = 2,097,152 pixels, C = 32 channels, S = 8192 segments.
// R1: 64M f32 atomics ~310 us -> sort path. R5: fixed-capacity buckets
//   (order[s*CAP+pos], pos=atomicAdd(cursor[s])), counts = final cursors.
// R6 FAILED (452 us): fp16 bucket-transpose. Scattered 64B row writes are
//   128B-line RMW, 512 MB buckets exceed L3 -> added ~250 MB of DRAM traffic.
//   Reverted.
// R7 (this): x (256 MB) == Infinity Cache capacity, but is COLD each iter
//   (1 GiB ws poison flushes MALL) and R5's gather used nontemporal x loads
//   (no-allocate hint). Fuse a streaming PRIME of x into phase 1 (phase 1 only
//   reads 8 MB sp; streaming 256 MB costs ~42 us, overlapping the scatter).
//   Gather then uses TEMPORAL x loads -> random 128B reads served by MALL at
//   multi-TB/s instead of DRAM-activation-bound ~1.2 TB/s. order traffic is
//   nontemporal both ways so it doesn't evict x.

constexpr int C = 32;
constexpr int CAP = 1024;                     // bucket slots per segment

typedef float v4f __attribute__((ext_vector_type(4)));

// ---------- phase 1: bucket scatter + x MALL-prime (one pass) ----------
// Block of 256 threads scatters 1024 pixels' labels AND streams those same
// 1024 pixels' feature rows (128 KB, coalesced, temporal) to allocate x into
// the Infinity Cache for phase 2's random gather.
__global__ __launch_bounds__(256) void scatter_bucket_kernel(
    const int4* __restrict__ sp4, const v4f* __restrict__ x4,
    int* __restrict__ cursor,   // [S], pre-zeroed
    int* __restrict__ order,    // [S*CAP]
    int n4)                     // n/4
{
    const int t = blockIdx.x * blockDim.x + threadIdx.x;
    if (t < n4) {
        int4 v = sp4[t];
        int p = t << 2;
        int p0 = atomicAdd(&cursor[v.x], 1);
        int p1 = atomicAdd(&cursor[v.y], 1);
        int p2 = atomicAdd(&cursor[v.z], 1);
        int p3 = atomicAdd(&cursor[v.w], 1);
        // nontemporal: keep the 32 MB order array out of MALL (protect x)
        if (p0 < CAP) __builtin_nontemporal_store(p,     &order[v.x * CAP + p0]);
        if (p1 < CAP) __builtin_nontemporal_store(p + 1, &order[v.y * CAP + p1]);
        if (p2 < CAP) __builtin_nontemporal_store(p + 2, &order[v.z * CAP + p2]);
        if (p3 < CAP) __builtin_nontemporal_store(p + 3, &order[v.w * CAP + p3]);
    }

    // ---- MALL prime: stream this block's 1024-pixel slice of x (temporal) ----
    // v4f index range: [blockIdx*8192, blockIdx*8192 + 8192), lane-coalesced.
    const long long total4 = (long long)n4 * 32;      // n pixels * 8 v4f/row
    const long long base   = (long long)blockIdx.x * 8192 + threadIdx.x;
    v4f acc = {0.f, 0.f, 0.f, 0.f};
    #pragma unroll 4
    for (int j = 0; j < 32; ++j) {
        long long idx = base + (long long)j * 256;
        if (idx < total4) acc += x4[idx];             // temporal: allocates in MALL
    }
    // keep the loads live without any memory side effect (guide rule #17)
    asm volatile("" :: "v"(acc.x), "v"(acc.y), "v"(acc.z), "v"(acc.w));
}

// ---------- phase 2: per-segment gather + mean (4 waves/block, 1 seg/wave) ----------
// 4-deep software pipeline: 4 independent order->row chains, 4 KB in flight/wave.
// x loads are TEMPORAL (serve from MALL primed in phase 1).
__global__ __launch_bounds__(256) void segment_mean_kernel(const v4f* __restrict__ x4,
                                                           const int* __restrict__ order,
                                                           const int* __restrict__ cursor,
                                                           v4f* __restrict__ out4, int S) {
    const int wave = threadIdx.x >> 6;         // 0..3
    const int wt   = threadIdx.x & 63;         // lane in wave
    const int s    = blockIdx.x * 4 + wave;
    if (s >= S) return;
    const int cnt   = cursor[s];               // true pixel count for segment s
    const int lim   = (cnt < CAP) ? cnt : CAP; // memory-safety clamp
    const int start = s * CAP;
    const int slot  = wt >> 3;                 // 0..7 : pixel slot
    const int cg    = wt & 7;                  // 0..7 : float4 channel-group

    v4f acc = {0.f, 0.f, 0.f, 0.f};
    int i = slot;
    for (; i + 24 < lim; i += 32) {
        int p0 = __builtin_nontemporal_load(&order[start + i]);
        int p1 = __builtin_nontemporal_load(&order[start + i + 8]);
        int p2 = __builtin_nontemporal_load(&order[start + i + 16]);
        int p3 = __builtin_nontemporal_load(&order[start + i + 24]);
        v4f v0 = x4[p0 * 8 + cg];
        v4f v1 = x4[p1 * 8 + cg];
        v4f v2 = x4[p2 * 8 + cg];
        v4f v3 = x4[p3 * 8 + cg];
        acc += v0 + v1 + v2 + v3;
    }
    for (; i < lim; i += 8) {
        int p = __builtin_nontemporal_load(&order[start + i]);
        acc += x4[p * 8 + cg];
    }
    // Reduce across the 8 slots (lane stride 8) within the wave: +32, +16, +8
    #pragma unroll
    for (int d = 32; d >= 8; d >>= 1) {
        acc.x += __shfl_down(acc.x, d);
        acc.y += __shfl_down(acc.y, d);
        acc.z += __shfl_down(acc.z, d);
        acc.w += __shfl_down(acc.w, d);
    }
    if (wt < 8) {
        float inv = (cnt > 0) ? 1.0f / (float)cnt : 0.0f;
        out4[s * 8 + wt] = acc * inv;          // 128 B coalesced store per wave
    }
}

// ---------- fallback (atomic path) if workspace is too small ----------
__global__ void fb_scatter_kernel(const float* __restrict__ x, const int* __restrict__ sp,
                                  float* __restrict__ sums, float* __restrict__ fcounts,
                                  int n_pixels) {
    long long t = (long long)blockIdx.x * blockDim.x + threadIdx.x;
    long long p = t >> 5;
    int c = (int)(t & 31);
    if (p >= n_pixels) return;
    int label = sp[p];
    float v = x[p * C + c];
    atomicAdd(&sums[(long long)label * C + c], v);
    if (c == 0) atomicAdd(&fcounts[label], 1.0f);
}
__global__ void fb_divide_kernel(float* __restrict__ out, const float* __restrict__ fcounts,
                                 int total) {
    int t = blockIdx.x * blockDim.x + threadIdx.x;
    if (t >= total) return;
    out[t] = out[t] / fmaxf(fcounts[t >> 5], 1.0f);
}

extern "C" void kernel_launch(void* const* d_in, const int* in_sizes, int n_in,
                              void* d_out, int out_size, void* d_ws, size_t ws_size,
                              hipStream_t stream) {
    const float* x  = (const float*)d_in[0];
    const int*   sp = (const int*)d_in[1];
    const int n = in_sizes[1];
    const int S = out_size / C;

    const size_t need = (size_t)S * sizeof(int) + (size_t)S * CAP * sizeof(int);
    if (ws_size >= need && (n & 3) == 0) {
        int* cursor = (int*)d_ws;           // [S]
        int* order  = cursor + S;           // [S*CAP]

        hipMemsetAsync(cursor, 0, (size_t)S * sizeof(int), stream);
        const int n4 = n >> 2;
        scatter_bucket_kernel<<<(n4 + 255) / 256, 256, 0, stream>>>(
            (const int4*)sp, (const v4f*)x, cursor, order, n4);
        segment_mean_kernel<<<(S + 3) / 4, 256, 0, stream>>>(
            (const v4f*)x, order, cursor, (v4f*)d_out, S);
    } else {
        float* sums    = (float*)d_out;
        float* fcounts = (float*)d_ws;
        hipMemsetAsync(d_out, 0, sizeof(float) * (size_t)out_size, stream);
        hipMemsetAsync(fcounts, 0, sizeof(float) * (size_t)S, stream);
        long long total_threads = (long long)n * C;
        fb_scatter_kernel<<<dim3((unsigned)((total_threads + 255) / 256)), 256, 0, stream>>>(
            x, sp, sums, fcounts, n);
        fb_divide_kernel<<<(out_size + 255) / 256, 256, 0, stream>>>(sums, fcounts, out_size);
    }
}

// Round 3
// 471.296 us; speedup vs baseline: 1.1480x; 1.1480x over previous
//
#include <hip/hip_runtime.h>

// Segment mean via fixed-capacity bucket sort + atomic-free gather reduction.
// N = 2,097,152 pixels, C = 32 channels, S = 8192 segments.
// R1: 64M f32 atomics ~310 us -> sort path. R5: fixed-capacity buckets
//   (order[s*CAP+pos], pos=atomicAdd(cursor[s])), counts = final cursors.
// R6 FAILED (452): fp16 bucket-transpose -> 128B-line RMW on scattered 64B
//   writes + 512 MB out-of-L3 buckets. Reverted.
// R7 FAILED (541) but diagnostic: (a) nontemporal order stores bypassed L2
//   write-coalescing -> 2M x 64B HBM RMW = 280 MB extra traffic, scatter
//   40->237 us. (b) x-prime WORKED: x's 256 MB showed ~0 HBM FETCH (served
//   from Infinity Cache, resident across iters) and the temporal-load gather
//   dropped to ~130 us.
// R8 (this): keep prime + temporal x gather; revert order to plain temporal
//   stores/loads (hot 8 MB prefix lives in L2: 1 MB/XCD); deepen gather
//   pipeline 4->8 chains (8 KB/wave in flight) against MALL-hit latency.

constexpr int C = 32;
constexpr int CAP = 1024;                     // bucket slots per segment

typedef float v4f __attribute__((ext_vector_type(4)));

// ---------- phase 1: bucket scatter + x MALL-prime (one pass) ----------
__global__ __launch_bounds__(256) void scatter_bucket_kernel(
    const int4* __restrict__ sp4, const v4f* __restrict__ x4,
    int* __restrict__ cursor,   // [S], pre-zeroed
    int* __restrict__ order,    // [S*CAP]
    int n4)                     // n/4
{
    const int t = blockIdx.x * blockDim.x + threadIdx.x;
    if (t < n4) {
        int4 v = sp4[t];
        int p = t << 2;
        int p0 = atomicAdd(&cursor[v.x], 1);
        int p1 = atomicAdd(&cursor[v.y], 1);
        int p2 = atomicAdd(&cursor[v.z], 1);
        int p3 = atomicAdd(&cursor[v.w], 1);
        // PLAIN stores: hot order prefix (~1 MB/XCD-L2) coalesces in L2.
        if (p0 < CAP) order[v.x * CAP + p0] = p;
        if (p1 < CAP) order[v.y * CAP + p1] = p + 1;
        if (p2 < CAP) order[v.z * CAP + p2] = p + 2;
        if (p3 < CAP) order[v.w * CAP + p3] = p + 3;
    }

    // ---- MALL prime: stream this block's 1024-pixel slice of x (temporal) ----
    const long long total4 = (long long)n4 * 32;      // n pixels * 8 v4f/row
    const long long base   = (long long)blockIdx.x * 8192 + threadIdx.x;
    v4f acc = {0.f, 0.f, 0.f, 0.f};
    #pragma unroll 4
    for (int j = 0; j < 32; ++j) {
        long long idx = base + (long long)j * 256;
        if (idx < total4) acc += x4[idx];             // temporal: allocates in MALL
    }
    // keep the loads live without any memory side effect
    asm volatile("" :: "v"(acc.x), "v"(acc.y), "v"(acc.z), "v"(acc.w));
}

// ---------- phase 2: per-segment gather + mean (4 waves/block, 1 seg/wave) ----------
// 8-deep software pipeline: 8 independent order->row chains, 8 KB in flight/wave.
// x loads are TEMPORAL (serve from MALL; also re-allocate for next iteration).
__global__ __launch_bounds__(256) void segment_mean_kernel(const v4f* __restrict__ x4,
                                                           const int* __restrict__ order,
                                                           const int* __restrict__ cursor,
                                                           v4f* __restrict__ out4, int S) {
    const int wave = threadIdx.x >> 6;         // 0..3
    const int wt   = threadIdx.x & 63;         // lane in wave
    const int s    = blockIdx.x * 4 + wave;
    if (s >= S) return;
    const int cnt   = cursor[s];               // true pixel count for segment s
    const int lim   = (cnt < CAP) ? cnt : CAP; // memory-safety clamp
    const int start = s * CAP;
    const int slot  = wt >> 3;                 // 0..7 : pixel slot
    const int cg    = wt & 7;                  // 0..7 : float4 channel-group

    v4f acc = {0.f, 0.f, 0.f, 0.f};
    int i = slot;
    for (; i + 56 < lim; i += 64) {
        int p0 = order[start + i];
        int p1 = order[start + i + 8];
        int p2 = order[start + i + 16];
        int p3 = order[start + i + 24];
        int p4 = order[start + i + 32];
        int p5 = order[start + i + 40];
        int p6 = order[start + i + 48];
        int p7 = order[start + i + 56];
        v4f v0 = x4[p0 * 8 + cg];
        v4f v1 = x4[p1 * 8 + cg];
        v4f v2 = x4[p2 * 8 + cg];
        v4f v3 = x4[p3 * 8 + cg];
        v4f v4 = x4[p4 * 8 + cg];
        v4f v5 = x4[p5 * 8 + cg];
        v4f v6 = x4[p6 * 8 + cg];
        v4f v7 = x4[p7 * 8 + cg];
        acc += (v0 + v1) + (v2 + v3) + ((v4 + v5) + (v6 + v7));
    }
    for (; i < lim; i += 8) {
        int p = order[start + i];
        acc += x4[p * 8 + cg];
    }
    // Reduce across the 8 slots (lane stride 8) within the wave: +32, +16, +8
    #pragma unroll
    for (int d = 32; d >= 8; d >>= 1) {
        acc.x += __shfl_down(acc.x, d);
        acc.y += __shfl_down(acc.y, d);
        acc.z += __shfl_down(acc.z, d);
        acc.w += __shfl_down(acc.w, d);
    }
    if (wt < 8) {
        float inv = (cnt > 0) ? 1.0f / (float)cnt : 0.0f;
        out4[s * 8 + wt] = acc * inv;          // 128 B coalesced store per wave
    }
}

// ---------- fallback (atomic path) if workspace is too small ----------
__global__ void fb_scatter_kernel(const float* __restrict__ x, const int* __restrict__ sp,
                                  float* __restrict__ sums, float* __restrict__ fcounts,
                                  int n_pixels) {
    long long t = (long long)blockIdx.x * blockDim.x + threadIdx.x;
    long long p = t >> 5;
    int c = (int)(t & 31);
    if (p >= n_pixels) return;
    int label = sp[p];
    float v = x[p * C + c];
    atomicAdd(&sums[(long long)label * C + c], v);
    if (c == 0) atomicAdd(&fcounts[label], 1.0f);
}
__global__ void fb_divide_kernel(float* __restrict__ out, const float* __restrict__ fcounts,
                                 int total) {
    int t = blockIdx.x * blockDim.x + threadIdx.x;
    if (t >= total) return;
    out[t] = out[t] / fmaxf(fcounts[t >> 5], 1.0f);
}

extern "C" void kernel_launch(void* const* d_in, const int* in_sizes, int n_in,
                              void* d_out, int out_size, void* d_ws, size_t ws_size,
                              hipStream_t stream) {
    const float* x  = (const float*)d_in[0];
    const int*   sp = (const int*)d_in[1];
    const int n = in_sizes[1];
    const int S = out_size / C;

    const size_t need = (size_t)S * sizeof(int) + (size_t)S * CAP * sizeof(int);
    if (ws_size >= need && (n & 3) == 0) {
        int* cursor = (int*)d_ws;           // [S]
        int* order  = cursor + S;           // [S*CAP]

        hipMemsetAsync(cursor, 0, (size_t)S * sizeof(int), stream);
        const int n4 = n >> 2;
        scatter_bucket_kernel<<<(n4 + 255) / 256, 256, 0, stream>>>(
            (const int4*)sp, (const v4f*)x, cursor, order, n4);
        segment_mean_kernel<<<(S + 3) / 4, 256, 0, stream>>>(
            (const v4f*)x, order, cursor, (v4f*)d_out, S);
    } else {
        float* sums    = (float*)d_out;
        float* fcounts = (float*)d_ws;
        hipMemsetAsync(d_out, 0, sizeof(float) * (size_t)out_size, stream);
        hipMemsetAsync(fcounts, 0, sizeof(float) * (size_t)S, stream);
        long long total_threads = (long long)n * C;
        fb_scatter_kernel<<<dim3((unsigned)((total_threads + 255) / 256)), 256, 0, stream>>>(
            x, sp, sums, fcounts, n);
        fb_divide_kernel<<<(out_size + 255) / 256, 256, 0, stream>>>(sums, fcounts, out_size);
    }
}

// Round 4
// 453.623 us; speedup vs baseline: 1.1927x; 1.0390x over previous
//
#include <hip/hip_runtime.h>

// Segment mean via fixed-capacity bucket sort + atomic-free gather reduction.
// N = 2,097,152 pixels, C = 32 channels, S = 8192 segments.
// R1: 64M f32 atomics ~310 us -> sort path. R5 (418): fixed-capacity buckets
//   (order[s*CAP+pos], pos=atomicAdd(cursor[s])), counts = final cursors.
// R6 FAILED (452): fp16 bucket-transpose -> 64B scattered writes are 128B-line
//   RMW + 512 MB out-of-L3 buckets. Reverted.
// R7 FAILED (541): nontemporal order stores bypassed L2 write-coalescing
//   (+280 MB RMW traffic). Diagnostic: temporal-x gather ran ~130 us.
// R8 (471): plain order stores back; prime still costs +124 us in scatter and
//   its FETCH=135 MB (~= R7's) shows x is only ~50% MALL-resident when the
//   prime runs -- the prime double-pays x traffic for residency the gather's
//   own temporal loads establish for free.
// R9 (this): DROP the prime. Scatter = pure R5 (~40 us). Gather keeps
//   TEMPORAL x loads (the one-word diff vs R5's nontemporal) + 8-deep
//   pipeline; each iteration's gather re-allocates x into MALL for the next.
//   order reads + out stores nontemporal (single-use; protect x residency;
//   full-line stores so no RMW hazard).

constexpr int C = 32;
constexpr int CAP = 1024;                     // bucket slots per segment

typedef float v4f __attribute__((ext_vector_type(4)));

// ---------- phase 1: bucket scatter (single pass over labels) ----------
__global__ void scatter_bucket_kernel(const int4* __restrict__ sp4,
                                      int* __restrict__ cursor,   // [S], pre-zeroed
                                      int* __restrict__ order,    // [S*CAP]
                                      int n4) {
    int t = blockIdx.x * blockDim.x + threadIdx.x;
    if (t >= n4) return;
    int4 v = sp4[t];
    int p = t << 2;
    int p0 = atomicAdd(&cursor[v.x], 1);
    int p1 = atomicAdd(&cursor[v.y], 1);
    int p2 = atomicAdd(&cursor[v.z], 1);
    int p3 = atomicAdd(&cursor[v.w], 1);
    // PLAIN stores: hot order prefix (~1 MB per XCD-L2) coalesces in L2 (R7 lesson).
    if (p0 < CAP) order[v.x * CAP + p0] = p;
    if (p1 < CAP) order[v.y * CAP + p1] = p + 1;
    if (p2 < CAP) order[v.z * CAP + p2] = p + 2;
    if (p3 < CAP) order[v.w * CAP + p3] = p + 3;
}

// ---------- phase 2: per-segment gather + mean (4 waves/block, 1 seg/wave) ----------
// 8-deep software pipeline: 8 independent order->row chains, 8 KB in flight/wave.
// x loads TEMPORAL: serve from MALL when resident AND re-allocate x for the
// next iteration's gather (self-sustaining residency).
__global__ __launch_bounds__(256) void segment_mean_kernel(const v4f* __restrict__ x4,
                                                           const int* __restrict__ order,
                                                           const int* __restrict__ cursor,
                                                           v4f* __restrict__ out4, int S) {
    const int wave = threadIdx.x >> 6;         // 0..3
    const int wt   = threadIdx.x & 63;         // lane in wave
    const int s    = blockIdx.x * 4 + wave;
    if (s >= S) return;
    const int cnt   = cursor[s];               // true pixel count for segment s
    const int lim   = (cnt < CAP) ? cnt : CAP; // memory-safety clamp
    const int start = s * CAP;
    const int slot  = wt >> 3;                 // 0..7 : pixel slot
    const int cg    = wt & 7;                  // 0..7 : float4 channel-group

    v4f acc = {0.f, 0.f, 0.f, 0.f};
    int i = slot;
    for (; i + 56 < lim; i += 64) {
        int p0 = __builtin_nontemporal_load(&order[start + i]);
        int p1 = __builtin_nontemporal_load(&order[start + i + 8]);
        int p2 = __builtin_nontemporal_load(&order[start + i + 16]);
        int p3 = __builtin_nontemporal_load(&order[start + i + 24]);
        int p4 = __builtin_nontemporal_load(&order[start + i + 32]);
        int p5 = __builtin_nontemporal_load(&order[start + i + 40]);
        int p6 = __builtin_nontemporal_load(&order[start + i + 48]);
        int p7 = __builtin_nontemporal_load(&order[start + i + 56]);
        v4f v0 = x4[p0 * 8 + cg];
        v4f v1 = x4[p1 * 8 + cg];
        v4f v2 = x4[p2 * 8 + cg];
        v4f v3 = x4[p3 * 8 + cg];
        v4f v4 = x4[p4 * 8 + cg];
        v4f v5 = x4[p5 * 8 + cg];
        v4f v6 = x4[p6 * 8 + cg];
        v4f v7 = x4[p7 * 8 + cg];
        acc += (v0 + v1) + (v2 + v3) + ((v4 + v5) + (v6 + v7));
    }
    for (; i < lim; i += 8) {
        int p = __builtin_nontemporal_load(&order[start + i]);
        acc += x4[p * 8 + cg];
    }
    // Reduce across the 8 slots (lane stride 8) within the wave: +32, +16, +8
    #pragma unroll
    for (int d = 32; d >= 8; d >>= 1) {
        acc.x += __shfl_down(acc.x, d);
        acc.y += __shfl_down(acc.y, d);
        acc.z += __shfl_down(acc.z, d);
        acc.w += __shfl_down(acc.w, d);
    }
    if (wt < 8) {
        float inv = (cnt > 0) ? 1.0f / (float)cnt : 0.0f;
        // nontemporal full-line store (8 lanes x 16 B = 128 B): no RMW hazard,
        // keeps the write-once output from evicting x lines in MALL.
        v4f r = acc * inv;
        __builtin_nontemporal_store(r, &out4[s * 8 + wt]);
    }
}

// ---------- fallback (atomic path) if workspace is too small ----------
__global__ void fb_scatter_kernel(const float* __restrict__ x, const int* __restrict__ sp,
                                  float* __restrict__ sums, float* __restrict__ fcounts,
                                  int n_pixels) {
    long long t = (long long)blockIdx.x * blockDim.x + threadIdx.x;
    long long p = t >> 5;
    int c = (int)(t & 31);
    if (p >= n_pixels) return;
    int label = sp[p];
    float v = x[p * C + c];
    atomicAdd(&sums[(long long)label * C + c], v);
    if (c == 0) atomicAdd(&fcounts[label], 1.0f);
}
__global__ void fb_divide_kernel(float* __restrict__ out, const float* __restrict__ fcounts,
                                 int total) {
    int t = blockIdx.x * blockDim.x + threadIdx.x;
    if (t >= total) return;
    out[t] = out[t] / fmaxf(fcounts[t >> 5], 1.0f);
}

extern "C" void kernel_launch(void* const* d_in, const int* in_sizes, int n_in,
                              void* d_out, int out_size, void* d_ws, size_t ws_size,
                              hipStream_t stream) {
    const float* x  = (const float*)d_in[0];
    const int*   sp = (const int*)d_in[1];
    const int n = in_sizes[1];
    const int S = out_size / C;

    const size_t need = (size_t)S * sizeof(int) + (size_t)S * CAP * sizeof(int);
    if (ws_size >= need && (n & 3) == 0) {
        int* cursor = (int*)d_ws;           // [S]
        int* order  = cursor + S;           // [S*CAP]

        hipMemsetAsync(cursor, 0, (size_t)S * sizeof(int), stream);
        const int n4 = n >> 2;
        scatter_bucket_kernel<<<(n4 + 255) / 256, 256, 0, stream>>>(
            (const int4*)sp, cursor, order, n4);
        segment_mean_kernel<<<(S + 3) / 4, 256, 0, stream>>>(
            (const v4f*)x, order, cursor, (v4f*)d_out, S);
    } else {
        float* sums    = (float*)d_out;
        float* fcounts = (float*)d_ws;
        hipMemsetAsync(d_out, 0, sizeof(float) * (size_t)out_size, stream);
        hipMemsetAsync(fcounts, 0, sizeof(float) * (size_t)S, stream);
        long long total_threads = (long long)n * C;
        fb_scatter_kernel<<<dim3((unsigned)((total_threads + 255) / 256)), 256, 0, stream>>>(
            x, sp, sums, fcounts, n);
        fb_divide_kernel<<<(out_size + 255) / 256, 256, 0, stream>>>(sums, fcounts, out_size);
    }
}